// Round 2
// baseline (392.811 us; speedup 1.0000x reference)
//
#include <hip/hip_runtime.h>

#define BB 16
#define CC 128
#define NN 16384
#define BN_EPS 1e-5f

typedef unsigned short u16;
typedef short short8 __attribute__((ext_vector_type(8)));
typedef float floatx4 __attribute__((ext_vector_type(4)));

__device__ inline float b2f(u16 u) {
    union { unsigned int i; float f; } c; c.i = ((unsigned int)u) << 16; return c.f;
}
__device__ inline u16 f2b(float f) {  // round-to-nearest-even bf16
    union { float f; unsigned int i; } c; c.f = f;
    unsigned int r = c.i + 0x7fffu + ((c.i >> 16) & 1u);
    return (u16)(r >> 16);
}

// ---------------------------------------------------------------------------
// K1: partial Gram per (batch, k-chunk of 1024) via split-bf16 MFMA:
//     x = xh + xl (both exact bf16); E ~= Xh.Xh^T + Xh.Xl^T + Xl.Xh^T
//     (dropped Xl.Xl^T ~ 2^-18 relative). Also S[b][j] = sum_n x (fp32 exact).
// grid 256 = 16 batches x 16 chunks; non-atomic partial stores.
// ---------------------------------------------------------------------------
#define K1_LD 136   // 128 + 8 halfs pad
__global__ __launch_bounds__(256) void k_gram(const float* __restrict__ x,
                                              float* __restrict__ part,
                                              float* __restrict__ S)
{
    __shared__ u16 th[128 * K1_LD];
    __shared__ u16 tl[128 * K1_LD];
    __shared__ float rowsum[128];
    const int b     = blockIdx.x >> 4;
    const int chunk = blockIdx.x & 15;
    const int k0    = chunk * 1024;
    const int t     = threadIdx.x;
    const int w = t >> 6, lane = t & 63, quad = lane >> 4, colL = lane & 15;
    if (t < 128) rowsum[t] = 0.f;

    floatx4 acc[2][8];
#pragma unroll
    for (int rt = 0; rt < 2; ++rt)
#pragma unroll
        for (int ct = 0; ct < 8; ++ct) acc[rt][ct] = {0.f, 0.f, 0.f, 0.f};

    const float* xb = x + (size_t)b * CC * NN;
    for (int s = 0; s < 8; ++s) {
        const int ks = k0 + s * 128;
        __syncthreads();   // guards rowsum init / previous-stage frag reads
#pragma unroll
        for (int it = 0; it < 16; ++it) {
            int idx = it * 256 + t;
            int row = idx >> 5, c4 = idx & 31;
            float4 v = *(const float4*)(xb + (size_t)row * NN + ks + c4 * 4);
            u16 h0 = f2b(v.x), h1 = f2b(v.y), h2 = f2b(v.z), h3 = f2b(v.w);
            uint2 hv, lv;
            hv.x = (unsigned)h0 | ((unsigned)h1 << 16);
            hv.y = (unsigned)h2 | ((unsigned)h3 << 16);
            lv.x = (unsigned)f2b(v.x - b2f(h0)) | ((unsigned)f2b(v.y - b2f(h1)) << 16);
            lv.y = (unsigned)f2b(v.z - b2f(h2)) | ((unsigned)f2b(v.w - b2f(h3)) << 16);
            *(uint2*)&th[row * K1_LD + c4 * 4] = hv;
            *(uint2*)&tl[row * K1_LD + c4 * 4] = lv;
            float ps = v.x + v.y + v.z + v.w;
#pragma unroll
            for (int off = 16; off > 0; off >>= 1) ps += __shfl_down(ps, off, 32);
            if ((lane & 31) == 0) rowsum[row] += ps;   // one 32-group per row per iter
        }
        __syncthreads();
        const int rbase = w * 32;
#pragma unroll
        for (int ks2 = 0; ks2 < 4; ++ks2) {
            const int kk = ks2 * 32 + quad * 8;
            short8 a0h = *(const short8*)&th[(rbase + colL) * K1_LD + kk];
            short8 a1h = *(const short8*)&th[(rbase + 16 + colL) * K1_LD + kk];
            short8 a0l = *(const short8*)&tl[(rbase + colL) * K1_LD + kk];
            short8 a1l = *(const short8*)&tl[(rbase + 16 + colL) * K1_LD + kk];
#pragma unroll
            for (int ct = 0; ct < 8; ++ct) {
                short8 bh = *(const short8*)&th[(ct * 16 + colL) * K1_LD + kk];
                short8 bl = *(const short8*)&tl[(ct * 16 + colL) * K1_LD + kk];
                acc[0][ct] = __builtin_amdgcn_mfma_f32_16x16x32_bf16(a0h, bh, acc[0][ct], 0, 0, 0);
                acc[1][ct] = __builtin_amdgcn_mfma_f32_16x16x32_bf16(a1h, bh, acc[1][ct], 0, 0, 0);
                acc[0][ct] = __builtin_amdgcn_mfma_f32_16x16x32_bf16(a0l, bh, acc[0][ct], 0, 0, 0);
                acc[1][ct] = __builtin_amdgcn_mfma_f32_16x16x32_bf16(a1l, bh, acc[1][ct], 0, 0, 0);
                acc[0][ct] = __builtin_amdgcn_mfma_f32_16x16x32_bf16(a0h, bl, acc[0][ct], 0, 0, 0);
                acc[1][ct] = __builtin_amdgcn_mfma_f32_16x16x32_bf16(a1h, bl, acc[1][ct], 0, 0, 0);
            }
        }
    }
    // non-atomic partial store (C/D layout: col=lane&15, row=quad*4+r)
    float* pb = part + (size_t)(b * 16 + chunk) * CC * CC;
#pragma unroll
    for (int rt = 0; rt < 2; ++rt)
#pragma unroll
        for (int ct = 0; ct < 8; ++ct)
#pragma unroll
            for (int r = 0; r < 4; ++r) {
                int row = w * 32 + rt * 16 + quad * 4 + r;
                int col = ct * 16 + colL;
                pb[row * CC + col] = acc[rt][ct][r];
            }
    __syncthreads();   // rowsum writes (all waves) before read
    if (t < 128) atomicAdd(&S[b * CC + t], rowsum[t]);
}

// ---------------------------------------------------------------------------
// K1b: energy[b][ij] = sum over 16 k-chunk partials
// grid 1024 x 256 : one thread per output element
// ---------------------------------------------------------------------------
__global__ __launch_bounds__(256) void k_reduce(const float* __restrict__ part,
                                                float* __restrict__ energy)
{
    int idx = blockIdx.x * 256 + threadIdx.x;   // [0, 16*16384)
    int b = idx >> 14;
    int ij = idx & 16383;
    const float* p = part + (size_t)b * 16 * 16384 + ij;
    float s = 0.f;
#pragma unroll
    for (int c = 0; c < 16; ++c) s += p[c * 16384];
    energy[idx] = s;
}

// ---------------------------------------------------------------------------
// K2: per (b,i): att = softmax(-E[i,:]) (== softmax(rowmax-E)), store bf16;
//     meanacc[i] += sum_j att_j S[b,j];  e2acc[i] += att^T E att
// grid 2048 = 16*128, block 256
// ---------------------------------------------------------------------------
__global__ __launch_bounds__(256) void k_soft(const float* __restrict__ energy,
                                              const float* __restrict__ S,
                                              u16* __restrict__ attb,
                                              float* __restrict__ meanacc,
                                              float* __restrict__ e2acc)
{
    const int b = blockIdx.x >> 7;
    const int i = blockIdx.x & 127;
    const int t = threadIdx.x;
    __shared__ float att[128];
    __shared__ float red[256];
    const float* E = energy + b * CC * CC;

    float e = (t < 128) ? E[i * CC + t] : 3.0e38f;
    red[t] = e; __syncthreads();
    for (int s2 = 128; s2 > 0; s2 >>= 1) { if (t < s2) red[t] = fminf(red[t], red[t + s2]); __syncthreads(); }
    float emin = red[0]; __syncthreads();

    float a = (t < 128) ? expf(emin - e) : 0.f;
    red[t] = a; __syncthreads();
    for (int s2 = 128; s2 > 0; s2 >>= 1) { if (t < s2) red[t] += red[t + s2]; __syncthreads(); }
    float Z = red[0]; __syncthreads();

    float attf = 0.f;
    if (t < 128) {
        u16 ab = f2b(a / Z);
        attf = b2f(ab);                       // bf16-rounded: self-consistent with K3's MFMA
        attb[((size_t)b * CC + i) * CC + t] = ab;
        att[t] = attf;
    }
    float mp = (t < 128) ? attf * S[b * CC + t] : 0.f;
    red[t] = mp; __syncthreads();
    for (int s2 = 128; s2 > 0; s2 >>= 1) { if (t < s2) red[t] += red[t + s2]; __syncthreads(); }
    if (t == 0) atomicAdd(&meanacc[i], red[0]);
    __syncthreads();

    // e2 = sum_j att_j * (sum_k att_k E[j][k])
    const int j    = t & 127;
    const int half = t >> 7;
    const float* Ej = E + j * CC + half * 64;
    float inner = 0.f;
#pragma unroll 8
    for (int k = 0; k < 64; ++k) inner += att[half * 64 + k] * Ej[k];
    red[t] = inner; __syncthreads();
    float contrib = (t < 128) ? (red[t] + red[t + 128]) * att[t] : 0.f;
    __syncthreads();
    red[t] = contrib; __syncthreads();
    for (int s2 = 128; s2 > 0; s2 >>= 1) { if (t < s2) red[t] += red[t + s2]; __syncthreads(); }
    if (t == 0) atomicAdd(&e2acc[i], red[0]);
}

// ---------------------------------------------------------------------------
// K3: out[b][c][n] = alpha_c * (att[b] @ q_bf16[b])[c][n] + beta_c + x[b][c][n]
// grid 2048 = 16 batches x 128 n-chunks of 128, block 256
// ---------------------------------------------------------------------------
#define K3_LD 136
__global__ __launch_bounds__(256) void k_out(const float* __restrict__ x,
                                             const u16* __restrict__ attb,
                                             const float* __restrict__ meanacc,
                                             const float* __restrict__ e2acc,
                                             const float* __restrict__ gamma,
                                             const float* __restrict__ bnw,
                                             const float* __restrict__ bnb,
                                             float* __restrict__ out)
{
    __shared__ u16 attl[128 * K3_LD];
    __shared__ u16 qbf[128 * K3_LD];
    __shared__ float alpha[128];
    __shared__ float beta[128];
    const int b   = blockIdx.x >> 7;
    const int nn0 = (blockIdx.x & 127) * 128;
    const int t   = threadIdx.x;

    if (t < 128) {
        float g   = gamma[0];
        const float invBN = 1.f / (float)(BB * NN);
        float m   = g * meanacc[t] * invBN;
        float e2  = g * g * e2acc[t] * invBN;
        float var = e2 - m * m;
        float inv = rsqrtf(var + BN_EPS);
        float wv  = bnw[t];
        alpha[t] = g * wv * inv;
        beta[t]  = bnb[t] - m * wv * inv;
    }
    const u16* ab = attb + (size_t)b * CC * CC;
#pragma unroll
    for (int it = 0; it < 8; ++it) {
        int idx = it * 256 + t;
        int row = idx >> 4, c8 = idx & 15;
        *(uint4*)&attl[row * K3_LD + c8 * 8] = *(const uint4*)&ab[row * CC + c8 * 8];
    }
    const float* xb = x + (size_t)b * CC * NN + nn0;
#pragma unroll
    for (int it = 0; it < 16; ++it) {
        int idx = it * 256 + t;
        int row = idx >> 5, c4 = idx & 31;
        float4 v = *(const float4*)(xb + (size_t)row * NN + c4 * 4);
        uint2 hv;
        hv.x = (unsigned)f2b(v.x) | ((unsigned)f2b(v.y) << 16);
        hv.y = (unsigned)f2b(v.z) | ((unsigned)f2b(v.w) << 16);
        *(uint2*)&qbf[row * K3_LD + c4 * 4] = hv;
    }
    __syncthreads();

    const int w = t >> 6, lane = t & 63, quad = lane >> 4, colL = lane & 15;
    floatx4 acc[8][2];
#pragma unroll
    for (int rt = 0; rt < 8; ++rt) { acc[rt][0] = {0.f,0.f,0.f,0.f}; acc[rt][1] = {0.f,0.f,0.f,0.f}; }

#pragma unroll
    for (int ks = 0; ks < 4; ++ks) {
        const int kk = ks * 32 + quad * 8;
        short8 bf0, bf1;
#pragma unroll
        for (int j2 = 0; j2 < 8; ++j2) {   // B-frag column gather (broadcast-heavy, ~free)
            bf0[j2] = (short)qbf[(kk + j2) * K3_LD + w * 32 + colL];
            bf1[j2] = (short)qbf[(kk + j2) * K3_LD + w * 32 + 16 + colL];
        }
#pragma unroll
        for (int rt = 0; rt < 8; ++rt) {
            short8 af = *(const short8*)&attl[(rt * 16 + colL) * K3_LD + kk];
            acc[rt][0] = __builtin_amdgcn_mfma_f32_16x16x32_bf16(af, bf0, acc[rt][0], 0, 0, 0);
            acc[rt][1] = __builtin_amdgcn_mfma_f32_16x16x32_bf16(af, bf1, acc[rt][1], 0, 0, 0);
        }
    }

    float* ob = out + (size_t)b * CC * NN + nn0;
#pragma unroll
    for (int rt = 0; rt < 8; ++rt)
#pragma unroll
        for (int ct = 0; ct < 2; ++ct)
#pragma unroll
            for (int r = 0; r < 4; ++r) {
                int chn = rt * 16 + quad * 4 + r;
                int nn  = w * 32 + ct * 16 + colL;
                float v = alpha[chn] * acc[rt][ct][r] + beta[chn]
                        + xb[(size_t)chn * NN + nn];   // residual: exact fp32 (L1-hot)
                ob[(size_t)chn * NN + nn] = v;
            }
}

// ---------------------------------------------------------------------------
// ws layout (bytes):
//   [0,        16777216)  part    fp32 [16][16][128][128]  (Gram k-chunk partials)
//   [16777216, 17825792)  energy  fp32 [16][128][128]
//   [17825792, 17833984)  S       fp32 [16][128]
//   [17833984, 17834496)  meanacc fp32 [128]
//   [17834496, 17835008)  e2acc   fp32 [128]
//   [17835008, 18359296)  attb    bf16 [16][128][128]
// ---------------------------------------------------------------------------
extern "C" void kernel_launch(void* const* d_in, const int* in_sizes, int n_in,
                              void* d_out, int out_size, void* d_ws, size_t ws_size,
                              hipStream_t stream)
{
    const float* x     = (const float*)d_in[0];
    const float* gamma = (const float*)d_in[1];
    const float* bnw   = (const float*)d_in[2];
    const float* bnb   = (const float*)d_in[3];
    float* out = (float*)d_out;

    char* ws = (char*)d_ws;
    float* part    = (float*)(ws);
    float* energy  = (float*)(ws + 16777216);
    float* S       = (float*)(ws + 17825792);
    float* meanacc = (float*)(ws + 17833984);
    float* e2acc   = (float*)(ws + 17834496);
    u16*   attb    = (u16*)(ws + 17835008);

    hipMemsetAsync(ws + 17825792, 0, 9216, stream);   // zero S/meanacc/e2acc
    hipLaunchKernelGGL(k_gram,   dim3(256),  dim3(256), 0, stream, x, part, S);
    hipLaunchKernelGGL(k_reduce, dim3(1024), dim3(256), 0, stream, part, energy);
    hipLaunchKernelGGL(k_soft,   dim3(2048), dim3(256), 0, stream, energy, S, attb, meanacc, e2acc);
    hipLaunchKernelGGL(k_out,    dim3(2048), dim3(256), 0, stream, x, attb, meanacc, e2acc, gamma, bnw, bnb, out);
}

// Round 3
// 370.997 us; speedup vs baseline: 1.0588x; 1.0588x over previous
//
#include <hip/hip_runtime.h>

#define BB 16
#define CC 128
#define NN 16384
#define BN_EPS 1e-5f

typedef unsigned short u16;
typedef short short8 __attribute__((ext_vector_type(8)));
typedef float floatx4 __attribute__((ext_vector_type(4)));

__device__ inline float b2f(u16 u) {
    union { unsigned int i; float f; } c; c.i = ((unsigned int)u) << 16; return c.f;
}
__device__ inline u16 f2b(float f) {  // round-to-nearest-even bf16
    union { float f; unsigned int i; } c; c.f = f;
    unsigned int r = c.i + 0x7fffu + ((c.i >> 16) & 1u);
    return (u16)(r >> 16);
}

// ---------------------------------------------------------------------------
// K1: Gram via split-bf16 MFMA (E ~= XhXh^T + XhXl^T + XlXh^T), atomicAdd
//     straight into energy. S[b][j] = sum_n x (register-accumulated).
// grid 1024 = 16 batches x 64 chunks of 256 cols; 4 stages of 64.
// LDS 2 x 128x72 halfs = 36.9 KB -> 4 blocks/CU (16 waves/CU).
// ---------------------------------------------------------------------------
#define K1_LD 72   // 64 + 8 halfs pad (144 B rows, 16B-aligned)
__global__ __launch_bounds__(256, 4) void k_gram(const float* __restrict__ x,
                                                 float* __restrict__ energy,
                                                 float* __restrict__ S)
{
    __shared__ u16 th[128 * K1_LD];
    __shared__ u16 tl[128 * K1_LD];
    const int b     = blockIdx.x >> 6;
    const int chunk = blockIdx.x & 63;
    const int k0    = chunk * 256;
    const int t     = threadIdx.x;
    const int w = t >> 6, lane = t & 63, quad = lane >> 4, colL = lane & 15;

    floatx4 acc[2][8];
#pragma unroll
    for (int rt = 0; rt < 2; ++rt)
#pragma unroll
        for (int ct = 0; ct < 8; ++ct) acc[rt][ct] = {0.f, 0.f, 0.f, 0.f};
    float rs[8];
#pragma unroll
    for (int it = 0; it < 8; ++it) rs[it] = 0.f;

    const float* xb = x + (size_t)b * CC * NN;
    const int rrow = t >> 4;        // thread's fixed row residue (0..15)
    const int c4   = t & 15;        // thread's fixed col slot
    for (int s = 0; s < 4; ++s) {
        const int ks = k0 + s * 64;
        __syncthreads();   // guard previous-stage fragment reads
#pragma unroll
        for (int it = 0; it < 8; ++it) {
            int row = it * 16 + rrow;
            float4 v = *(const float4*)(xb + (size_t)row * NN + ks + c4 * 4);
            u16 h0 = f2b(v.x), h1 = f2b(v.y), h2 = f2b(v.z), h3 = f2b(v.w);
            uint2 hv, lv;
            hv.x = (unsigned)h0 | ((unsigned)h1 << 16);
            hv.y = (unsigned)h2 | ((unsigned)h3 << 16);
            lv.x = (unsigned)f2b(v.x - b2f(h0)) | ((unsigned)f2b(v.y - b2f(h1)) << 16);
            lv.y = (unsigned)f2b(v.z - b2f(h2)) | ((unsigned)f2b(v.w - b2f(h3)) << 16);
            *(uint2*)&th[row * K1_LD + c4 * 4] = hv;
            *(uint2*)&tl[row * K1_LD + c4 * 4] = lv;
            rs[it] += (v.x + v.y) + (v.z + v.w);
        }
        __syncthreads();
        const int rbase = w * 32;
#pragma unroll
        for (int ks2 = 0; ks2 < 2; ++ks2) {
            const int kk = ks2 * 32 + quad * 8;
            short8 a0h = *(const short8*)&th[(rbase + colL) * K1_LD + kk];
            short8 a1h = *(const short8*)&th[(rbase + 16 + colL) * K1_LD + kk];
            short8 a0l = *(const short8*)&tl[(rbase + colL) * K1_LD + kk];
            short8 a1l = *(const short8*)&tl[(rbase + 16 + colL) * K1_LD + kk];
#pragma unroll
            for (int ct = 0; ct < 8; ++ct) {
                short8 bh = *(const short8*)&th[(ct * 16 + colL) * K1_LD + kk];
                short8 bl = *(const short8*)&tl[(ct * 16 + colL) * K1_LD + kk];
                acc[0][ct] = __builtin_amdgcn_mfma_f32_16x16x32_bf16(a0h, bh, acc[0][ct], 0, 0, 0);
                acc[1][ct] = __builtin_amdgcn_mfma_f32_16x16x32_bf16(a1h, bh, acc[1][ct], 0, 0, 0);
                acc[0][ct] = __builtin_amdgcn_mfma_f32_16x16x32_bf16(a0l, bh, acc[0][ct], 0, 0, 0);
                acc[1][ct] = __builtin_amdgcn_mfma_f32_16x16x32_bf16(a1l, bh, acc[1][ct], 0, 0, 0);
                acc[0][ct] = __builtin_amdgcn_mfma_f32_16x16x32_bf16(a0h, bl, acc[0][ct], 0, 0, 0);
                acc[1][ct] = __builtin_amdgcn_mfma_f32_16x16x32_bf16(a1h, bl, acc[1][ct], 0, 0, 0);
            }
        }
    }
    // accumulate Gram tile (C/D layout: col=lane&15, row=quad*4+r)
    float* eb = energy + b * CC * CC;
#pragma unroll
    for (int rt = 0; rt < 2; ++rt)
#pragma unroll
        for (int ct = 0; ct < 8; ++ct)
#pragma unroll
            for (int r = 0; r < 4; ++r) {
                int row = w * 32 + rt * 16 + quad * 4 + r;
                int col = ct * 16 + colL;
                atomicAdd(&eb[row * CC + col], acc[rt][ct][r]);
            }
    // row-sums: reduce rs[it] over the 16 threads sharing row it*16 + w*4 + quad
#pragma unroll
    for (int it = 0; it < 8; ++it) {
        float ps = rs[it];
#pragma unroll
        for (int off = 8; off > 0; off >>= 1) ps += __shfl_down(ps, off, 16);
        if (colL == 0) atomicAdd(&S[b * CC + it * 16 + w * 4 + quad], ps);
    }
}

// ---------------------------------------------------------------------------
// K2: per (b,i): att = softmax(-E[i,:]), store bf16;
//     meanacc[i] += sum_j att_j S[b,j];  e2acc[i] += att^T E att
// grid 2048 = 16*128, block 256
// ---------------------------------------------------------------------------
__global__ __launch_bounds__(256) void k_soft(const float* __restrict__ energy,
                                              const float* __restrict__ S,
                                              u16* __restrict__ attb,
                                              float* __restrict__ meanacc,
                                              float* __restrict__ e2acc)
{
    const int b = blockIdx.x >> 7;
    const int i = blockIdx.x & 127;
    const int t = threadIdx.x;
    __shared__ float att[128];
    __shared__ float red[256];
    const float* E = energy + b * CC * CC;

    float e = (t < 128) ? E[i * CC + t] : 3.0e38f;
    red[t] = e; __syncthreads();
    for (int s2 = 128; s2 > 0; s2 >>= 1) { if (t < s2) red[t] = fminf(red[t], red[t + s2]); __syncthreads(); }
    float emin = red[0]; __syncthreads();

    float a = (t < 128) ? expf(emin - e) : 0.f;
    red[t] = a; __syncthreads();
    for (int s2 = 128; s2 > 0; s2 >>= 1) { if (t < s2) red[t] += red[t + s2]; __syncthreads(); }
    float Z = red[0]; __syncthreads();

    float attf = 0.f;
    if (t < 128) {
        u16 ab = f2b(a / Z);
        attf = b2f(ab);                       // bf16-rounded: self-consistent with K3's MFMA
        attb[((size_t)b * CC + i) * CC + t] = ab;
        att[t] = attf;
    }
    float mp = (t < 128) ? attf * S[b * CC + t] : 0.f;
    red[t] = mp; __syncthreads();
    for (int s2 = 128; s2 > 0; s2 >>= 1) { if (t < s2) red[t] += red[t + s2]; __syncthreads(); }
    if (t == 0) atomicAdd(&meanacc[i], red[0]);
    __syncthreads();

    // e2 = sum_j att_j * (sum_k att_k E[j][k])
    const int j    = t & 127;
    const int half = t >> 7;
    const float* Ej = E + j * CC + half * 64;
    float inner = 0.f;
#pragma unroll 8
    for (int k = 0; k < 64; ++k) inner += att[half * 64 + k] * Ej[k];
    red[t] = inner; __syncthreads();
    float contrib = (t < 128) ? (red[t] + red[t + 128]) * att[t] : 0.f;
    __syncthreads();
    red[t] = contrib; __syncthreads();
    for (int s2 = 128; s2 > 0; s2 >>= 1) { if (t < s2) red[t] += red[t + s2]; __syncthreads(); }
    if (t == 0) atomicAdd(&e2acc[i], red[0]);
}

// ---------------------------------------------------------------------------
// K3: out = alpha_c * (att @ q_bf16) + beta_c + x.
// q staged TRANSPOSED (n-major) via register 4x4 transpose, rotation-swizzled
// so B-fragments are aligned ds_read_b128. att A-frags read from global (L1/L2
// hot: 32 KB/batch shared by 128 blocks). LDS 35.8 KB -> 4 blocks/CU.
// grid 2048 = 16 batches x 128 n-chunks of 128, block 256
// ---------------------------------------------------------------------------
#define K3_LD 136   // k-extent 128 + 8 pad (272 B rows, 16B-aligned)
__global__ __launch_bounds__(256, 4) void k_out(const float* __restrict__ x,
                                                const u16* __restrict__ attb,
                                                const float* __restrict__ meanacc,
                                                const float* __restrict__ e2acc,
                                                const float* __restrict__ gamma,
                                                const float* __restrict__ bnw,
                                                const float* __restrict__ bnb,
                                                float* __restrict__ out)
{
    __shared__ u16 qT[128 * K3_LD];   // [n][k], k-group rotated by n
    __shared__ float alpha[128];
    __shared__ float beta[128];
    const int b   = blockIdx.x >> 7;
    const int nn0 = (blockIdx.x & 127) * 128;
    const int t   = threadIdx.x;

    if (t < 128) {
        float g   = gamma[0];
        const float invBN = 1.f / (float)(BB * NN);
        float m   = g * meanacc[t] * invBN;
        float e2  = g * g * e2acc[t] * invBN;
        float var = e2 - m * m;
        float inv = rsqrtf(var + BN_EPS);
        float wv  = bnw[t];
        alpha[t] = g * wv * inv;
        beta[t]  = bnb[t] - m * wv * inv;
    }

    const float* xb = x + (size_t)b * CC * NN + nn0;
    const int n0 = (t & 31) * 4;
#pragma unroll
    for (int rep = 0; rep < 4; ++rep) {
        const int c0 = ((t >> 5) + rep * 8) * 4;   // k-rows c0..c0+3
        float4 f0 = *(const float4*)(xb + (size_t)(c0 + 0) * NN + n0);
        float4 f1 = *(const float4*)(xb + (size_t)(c0 + 1) * NN + n0);
        float4 f2 = *(const float4*)(xb + (size_t)(c0 + 2) * NN + n0);
        float4 f3 = *(const float4*)(xb + (size_t)(c0 + 3) * NN + n0);
        const float fx[4] = {f0.x, f1.x, f2.x, f3.x};
        const float fy[4] = {f0.y, f1.y, f2.y, f3.y};
        const float fz[4] = {f0.z, f1.z, f2.z, f3.z};
        const float fw[4] = {f0.w, f1.w, f2.w, f3.w};
        const float* cols[4] = {fx, fy, fz, fw};
#pragma unroll
        for (int jn = 0; jn < 4; ++jn) {           // n = n0+jn: halfs k=c0..c0+3
            int n = n0 + jn;
            int g = ((c0 >> 3) + n) & 15;
            uint2 v;
            v.x = (unsigned)f2b(cols[jn][0]) | ((unsigned)f2b(cols[jn][1]) << 16);
            v.y = (unsigned)f2b(cols[jn][2]) | ((unsigned)f2b(cols[jn][3]) << 16);
            *(uint2*)&qT[n * K3_LD + g * 8 + (c0 & 7)] = v;
        }
    }
    __syncthreads();

    const int w = t >> 6, lane = t & 63, quad = lane >> 4, colL = lane & 15;
    const u16* ag = attb + (size_t)b * CC * CC;
    floatx4 acc[8][2];
#pragma unroll
    for (int rt = 0; rt < 8; ++rt) { acc[rt][0] = {0.f,0.f,0.f,0.f}; acc[rt][1] = {0.f,0.f,0.f,0.f}; }

#pragma unroll
    for (int ks = 0; ks < 4; ++ks) {
        const int kk = ks * 32 + quad * 8;
        const int n_a = w * 32 + colL;
        const int n_b = n_a + 16;
        short8 bf0 = *(const short8*)&qT[n_a * K3_LD + ((((kk) >> 3) + n_a) & 15) * 8];
        short8 bf1 = *(const short8*)&qT[n_b * K3_LD + ((((kk) >> 3) + n_b) & 15) * 8];
#pragma unroll
        for (int rt = 0; rt < 8; ++rt) {
            short8 af = *(const short8*)&ag[(rt * 16 + colL) * CC + kk];   // L1-hot
            acc[rt][0] = __builtin_amdgcn_mfma_f32_16x16x32_bf16(af, bf0, acc[rt][0], 0, 0, 0);
            acc[rt][1] = __builtin_amdgcn_mfma_f32_16x16x32_bf16(af, bf1, acc[rt][1], 0, 0, 0);
        }
    }

    float* ob = out + (size_t)b * CC * NN + nn0;
#pragma unroll
    for (int rt = 0; rt < 8; ++rt)
#pragma unroll
        for (int ct = 0; ct < 2; ++ct)
#pragma unroll
            for (int r = 0; r < 4; ++r) {
                int chn = rt * 16 + quad * 4 + r;
                int nn  = w * 32 + ct * 16 + colL;
                float v = alpha[chn] * acc[rt][ct][r] + beta[chn]
                        + xb[(size_t)chn * NN + nn];   // residual fp32 (L1-hot re-read)
                ob[(size_t)chn * NN + nn] = v;
            }
}

// ---------------------------------------------------------------------------
// ws layout (bytes):
//   [0,       1048576)  energy  fp32 [16][128][128]  (atomic-accumulated)
//   [1048576, 1056768)  S       fp32 [16][128]
//   [1056768, 1057280)  meanacc fp32 [128]
//   [1057280, 1057792)  e2acc   fp32 [128]
//   [1057792, 1582080)  attb    bf16 [16][128][128]
// ---------------------------------------------------------------------------
extern "C" void kernel_launch(void* const* d_in, const int* in_sizes, int n_in,
                              void* d_out, int out_size, void* d_ws, size_t ws_size,
                              hipStream_t stream)
{
    const float* x     = (const float*)d_in[0];
    const float* gamma = (const float*)d_in[1];
    const float* bnw   = (const float*)d_in[2];
    const float* bnb   = (const float*)d_in[3];
    float* out = (float*)d_out;

    char* ws = (char*)d_ws;
    float* energy  = (float*)(ws);
    float* S       = (float*)(ws + 1048576);
    float* meanacc = (float*)(ws + 1056768);
    float* e2acc   = (float*)(ws + 1057280);
    u16*   attb    = (u16*)(ws + 1057792);

    hipMemsetAsync(ws, 0, 1057792, stream);   // zero energy/S/accumulators
    hipLaunchKernelGGL(k_gram, dim3(1024), dim3(256), 0, stream, x, energy, S);
    hipLaunchKernelGGL(k_soft, dim3(2048), dim3(256), 0, stream, energy, S, attb, meanacc, e2acc);
    hipLaunchKernelGGL(k_out,  dim3(2048), dim3(256), 0, stream, x, attb, meanacc, e2acc, gamma, bnw, bnb, out);
}